// Round 3
// baseline (460.071 us; speedup 1.0000x reference)
//
#include <hip/hip_runtime.h>
#include <math.h>

// Problem constants (B=4, L=8192, SEG=2048, RATE=4, D=768)
#define SEGLEN 2048
#define SRATE 4
#define DIM 768
#define BATCH 4
#define LFULL 8192
#define LSP 2048                 // sparsified length per batch (4 segs * 512)
#define NROWS (BATCH * LSP)      // 8192 total sparsified rows
#define LN_EPS 1e-5f
#define ATT_SCALE 0.03608439182435161f   // 1/sqrt(768)

typedef __attribute__((ext_vector_type(8))) short s16x8;
typedef __attribute__((ext_vector_type(4))) float f32x4;

__device__ __forceinline__ ushort f2bf(float f) {
    unsigned u = __float_as_uint(f);
    u += 0x7fffu + ((u >> 16) & 1u);      // RNE
    return (ushort)(u >> 16);
}
__device__ __forceinline__ float bf2f(ushort h) {
    return __uint_as_float(((unsigned)h) << 16);
}

// async global->LDS, 16B per lane. LDS dest is wave-uniform base + lane*16.
__device__ __forceinline__ void ld_lds16(const ushort* g, ushort* l) {
    __builtin_amdgcn_global_load_lds(
        (const __attribute__((address_space(1))) void*)g,
        (__attribute__((address_space(3))) void*)l, 16, 0, 0);
}

// ---------------------------------------------------------------------------
// Gather sparsified rows (every RATE-th within each segment) + fp32->bf16.
// z selects Q/K/V. dst r = b*2048 + seg*512 + j <- src[b*8192 + seg*2048 + j*4]
// ---------------------------------------------------------------------------
__global__ void pack3(const float* __restrict__ Q, const float* __restrict__ Ks,
                      const float* __restrict__ V, ushort* __restrict__ X) {
    const float* src = blockIdx.z == 0 ? Q : blockIdx.z == 1 ? Ks : V;
    ushort* dst = X + (long)blockIdx.z * (NROWS * DIM);
    int idx = blockIdx.x * 256 + threadIdx.x;        // one per 4 elements
    int r  = idx / (DIM / 4);
    int dg = idx - r * (DIM / 4);
    int bb = r >> 11;            // /2048
    int s  = r & 2047;
    int seg = s >> 9;            // /512
    int j   = s & 511;
    long srow = (long)bb * LFULL + seg * SEGLEN + j * SRATE;
    float4 f = *(const float4*)(src + srow * DIM + dg * 4);
    ushort4 o;
    o.x = f2bf(f.x); o.y = f2bf(f.y); o.z = f2bf(f.z); o.w = f2bf(f.w);
    *(ushort4*)(dst + (long)r * DIM + dg * 4) = o;
}

// weights fp32 -> bf16, z selects Wq/Wk/Wv; dst contiguous
__global__ void conv3(const float* __restrict__ Wq, const float* __restrict__ Wk,
                      const float* __restrict__ Wv, ushort* __restrict__ W) {
    const float* src = blockIdx.z == 0 ? Wq : blockIdx.z == 1 ? Wk : Wv;
    ushort* dst = W + (long)blockIdx.z * (DIM * DIM);
    int idx = blockIdx.x * 256 + threadIdx.x;
    float4 f = *(const float4*)(src + (long)idx * 4);
    ushort4 o;
    o.x = f2bf(f.x); o.y = f2bf(f.y); o.z = f2bf(f.z); o.w = f2bf(f.w);
    *(ushort4*)(dst + (long)idx * 4) = o;
}

// ---------------------------------------------------------------------------
// BT-GEMM: C[i][j] = sum_k A[i][k] * B[j][k]  (both operands K-contiguous bf16)
// 128x128 tile, BK=64, 256 thr = 4 waves (2x2), each wave 64x64 (4x4 MFMA).
// XCD-band swizzle: xcd = flat&7 gets a contiguous tile range -> per-XCD L2
// holds one A-band + one B operand. LDS layout column-grouped (slab = 8 rows,
// within slab: [kgroup][row] 16B chunks) -> ds_read_b128 bank = f(row&7) only
// -> 2 lanes/bank = conflict-free. Staged by source-permuted global_load_lds.
// MODE 0: z<2 -> bf16 row-major to Cb+z*sC; z==2 -> transposed vT to Cb2 [proj]
// MODE 2: e=__expf(acc*scale); bf16 P row-major + atomicAdd row-sums     [QK]
// MODE 3: split-K: z=(batch,half); fp32 row-major to (half? Cf2 : Cf)   [PV]
// ---------------------------------------------------------------------------
#define GTILE 128
#define GBK 64

template<int MODE>
__global__ __launch_bounds__(256) void gemm_bt(
    const ushort* __restrict__ Ag, const ushort* __restrict__ Bg,
    ushort* __restrict__ Cb, ushort* __restrict__ Cb2,
    float* __restrict__ Cf, float* __restrict__ Cf2, float* __restrict__ lsum,
    int M, int N, int K, int lda, int ldb, long sA, long sB, long sC,
    int ldc, float scale)
{
    __shared__ ushort As[GTILE * GBK];   // 16 KB each
    __shared__ ushort Bs[GTILE * GBK];

    // XCD-band swizzle (total blocks % 8 == 0 for all launches here)
    const int CT = gridDim.x, RT = gridDim.y;
    const int nt = CT * RT;
    const int total = nt * gridDim.z;
    int g = (blockIdx.z * RT + blockIdx.y) * CT + blockIdx.x;
    g = (g & 7) * (total >> 3) + (g >> 3);
    const int z = g / nt;
    const int rem = g - z * nt;
    const int by = rem / CT, bx = rem - by * CT;

    const int bz = (MODE == 3) ? (z >> 1) : z;
    const int hz = (MODE == 3) ? (z & 1) : 0;
    const ushort* A = Ag + (long)bz * sA + (long)hz * K;
    const ushort* B = Bg + (long)bz * sB + (long)hz * K;

    const int tid = threadIdx.x;
    const int rowBase = by * GTILE;
    const int colBase = bx * GTILE;
    const int wid = tid >> 6, lane = tid & 63;
    const int wm = wid >> 1, wn = wid & 1;
    const int quad = lane >> 4, lr = lane & 15;

    f32x4 acc[4][4] = {};

    // staging: wave wid owns A rows [wid*32, wid*32+32) = slabs wid*4+s (8 rows
    // each), same for B. lane l fetches row (l&7) of the slab, kgroup (l>>3).
    const ushort* gA = A + (long)(rowBase + wid * 32 + (lane & 7)) * lda + (lane >> 3) * 8;
    const ushort* gB = B + (long)(colBase + wid * 32 + (lane & 7)) * ldb + (lane >> 3) * 8;
    ushort* lA = As + wid * 2048;   // wave-uniform; 4 slabs x 512 ushorts
    ushort* lB = Bs + wid * 2048;

    // frag read index: row = wm*64 + t*16 + lr; slab = row>>3; within slab:
    // chunk (h*4+quad), row&7.   (lr&7)*8 + (h*4+quad)*64 + slab*512
    const int fra = (wm * 8 + (lr >> 3)) * 512 + (lr & 7) * 8;
    const int frb = (wn * 8 + (lr >> 3)) * 512 + (lr & 7) * 8;

    for (int k0 = 0; k0 < K; k0 += GBK) {
        __syncthreads();                       // prev iter's ds_reads done
#pragma unroll
        for (int s = 0; s < 4; s++) {
            ld_lds16(gA + (long)s * 8 * lda + k0, lA + s * 512);
            ld_lds16(gB + (long)s * 8 * ldb + k0, lB + s * 512);
        }
        __syncthreads();                       // drains vmcnt before barrier

#pragma unroll
        for (int h = 0; h < 2; h++) {
            s16x8 af[4], bfm[4];
#pragma unroll
            for (int t = 0; t < 4; t++)
                af[t] = *(const s16x8*)&As[fra + t * 1024 + (h * 4 + quad) * 64];
#pragma unroll
            for (int t = 0; t < 4; t++)
                bfm[t] = *(const s16x8*)&Bs[frb + t * 1024 + (h * 4 + quad) * 64];
#pragma unroll
            for (int i = 0; i < 4; i++)
#pragma unroll
                for (int j = 0; j < 4; j++)
                    acc[i][j] = __builtin_amdgcn_mfma_f32_16x16x32_bf16(af[i], bfm[j], acc[i][j], 0, 0, 0);
        }
    }

    // Epilogue. D mapping: col = lane&15 (B-operand row), row = quad*4+reg.
    if (MODE == 0) {
        if (z < 2) {
            ushort* Cz = Cb + (long)z * sC;
#pragma unroll
            for (int i = 0; i < 4; i++) {
                int r0 = rowBase + wm * 64 + i * 16 + quad * 4;
#pragma unroll
                for (int j = 0; j < 4; j++) {
                    int c = colBase + wn * 64 + j * 16 + lr;
#pragma unroll
                    for (int reg = 0; reg < 4; reg++)
                        Cz[(long)(r0 + reg) * ldc + c] = f2bf(acc[i][j][reg]);
                }
            }
        } else {
            // v-projection: store transposed vT[b][col][row]
#pragma unroll
            for (int i = 0; i < 4; i++) {
                int r0 = rowBase + wm * 64 + i * 16 + quad * 4;
                int bidx = r0 >> 11;
                int jj = r0 & 2047;
                ushort* Cz = Cb2 + (long)bidx * DIM * LSP;
#pragma unroll
                for (int j = 0; j < 4; j++) {
                    int c = colBase + wn * 64 + j * 16 + lr;
                    ushort4 o;
                    o.x = f2bf(acc[i][j][0]); o.y = f2bf(acc[i][j][1]);
                    o.z = f2bf(acc[i][j][2]); o.w = f2bf(acc[i][j][3]);
                    *(ushort4*)(Cz + (long)c * LSP + jj) = o;
                }
            }
        }
    } else if (MODE == 2) {
        ushort* Cz = Cb + (long)z * sC;
        float* lz = lsum + (long)z * M;
#pragma unroll
        for (int i = 0; i < 4; i++) {
            int r0 = rowBase + wm * 64 + i * 16 + quad * 4;
#pragma unroll
            for (int reg = 0; reg < 4; reg++) {
                float s = 0.f;
#pragma unroll
                for (int j = 0; j < 4; j++) {
                    int c = colBase + wn * 64 + j * 16 + lr;
                    float e = __expf(acc[i][j][reg] * scale);  // |logit|<=sqrt(768): no max needed
                    s += e;
                    Cz[(long)(r0 + reg) * ldc + c] = f2bf(e);
                }
                for (int m = 1; m < 16; m <<= 1) s += __shfl_xor(s, m, 64);
                if (lr == 0) atomicAdd(&lz[r0 + reg], s);
            }
        }
    } else { // MODE 3 split-K
        float* Cz = (hz ? Cf2 : Cf) + (long)bz * sC;
#pragma unroll
        for (int i = 0; i < 4; i++) {
            int r0 = rowBase + wm * 64 + i * 16 + quad * 4;
#pragma unroll
            for (int j = 0; j < 4; j++) {
                int c = colBase + wn * 64 + j * 16 + lr;
#pragma unroll
                for (int reg = 0; reg < 4; reg++)
                    Cz[(long)(r0 + reg) * ldc + c] = acc[i][j][reg];
            }
        }
    }
}

// ---------------------------------------------------------------------------
// In-place LayerNorm over DIM=768 bf16 values. One wave per row (12 elem/lane).
// ---------------------------------------------------------------------------
__global__ __launch_bounds__(256) void ln_inplace(
    ushort* __restrict__ X, const float* __restrict__ gamma,
    const float* __restrict__ beta)
{
    int wid = threadIdx.x >> 6, lane = threadIdx.x & 63;
    int row = blockIdx.x * 4 + wid;
    ushort* xp = X + (long)row * DIM;
    float v[12];
    float s = 0.f;
#pragma unroll
    for (int c = 0; c < 12; c++) { v[c] = bf2f(xp[c * 64 + lane]); s += v[c]; }
    for (int m = 1; m < 64; m <<= 1) s += __shfl_xor(s, m, 64);
    float mean = s * (1.0f / 768.0f);
    float q = 0.f;
#pragma unroll
    for (int c = 0; c < 12; c++) { float d = v[c] - mean; q += d * d; }
    for (int m = 1; m < 64; m <<= 1) q += __shfl_xor(q, m, 64);
    float rstd = rsqrtf(q * (1.0f / 768.0f) + LN_EPS);
#pragma unroll
    for (int c = 0; c < 12; c++) {
        int idx = c * 64 + lane;
        float y = (v[c] - mean) * rstd * gamma[idx] + beta[idx];
        xp[idx] = f2bf(y);
    }
}

// ---------------------------------------------------------------------------
// out[row] = softmax_over_d( (O0[row]+O1[row]) / l[row] ). One wave per row.
// ---------------------------------------------------------------------------
__global__ __launch_bounds__(256) void final_softmax(
    const float* __restrict__ O0, const float* __restrict__ O1,
    const float* __restrict__ l, float* __restrict__ out)
{
    int wid = threadIdx.x >> 6, lane = threadIdx.x & 63;
    int row = blockIdx.x * 4 + wid;
    long base = (long)row * DIM;
    float inv = 1.0f / l[row];
    float v[12]; float mx = -1e30f;
#pragma unroll
    for (int c = 0; c < 12; c++) {
        v[c] = (O0[base + c * 64 + lane] + O1[base + c * 64 + lane]) * inv;
        mx = fmaxf(mx, v[c]);
    }
    for (int m = 1; m < 64; m <<= 1) mx = fmaxf(mx, __shfl_xor(mx, m, 64));
    float s = 0.f;
#pragma unroll
    for (int c = 0; c < 12; c++) { v[c] = __expf(v[c] - mx); s += v[c]; }
    for (int m = 1; m < 64; m <<= 1) s += __shfl_xor(s, m, 64);
    float invs = 1.0f / s;
#pragma unroll
    for (int c = 0; c < 12; c++) out[base + c * 64 + lane] = v[c] * invs;
}

// ---------------------------------------------------------------------------
extern "C" void kernel_launch(void* const* d_in, const int* in_sizes, int n_in,
                              void* d_out, int out_size, void* d_ws, size_t ws_size,
                              hipStream_t stream)
{
    const float* Q  = (const float*)d_in[0];
    const float* K_ = (const float*)d_in[1];
    const float* V  = (const float*)d_in[2];
    const float* Wq = (const float*)d_in[3];
    const float* Wk = (const float*)d_in[4];
    const float* Wv = (const float*)d_in[5];
    const float* g  = (const float*)d_in[6];
    const float* b  = (const float*)d_in[7];
    float* out = (float*)d_out;

    char* ws = (char*)d_ws;
    // Workspace layout (bytes). Total ~104.3 MB.
    // P aliases X (lifetime-disjoint); O1 aliases qb+kb (dead after QK).
    ushort* Xq  = (ushort*)(ws + 0);            // 12,582,912 each (Xq,Xk,Xv contig)
    ushort* Wqb = (ushort*)(ws + 37748736);     // 1,179,648 each (contig)
    ushort* qb  = (ushort*)(ws + 41287680);     // 12,582,912 each (qb,kb contig)
    ushort* kb  = (ushort*)(ws + 53870592);
    ushort* vT  = (ushort*)(ws + 66453504);     // 12,582,912
    float*  O0  = (float*)(ws + 79036416);      // 25,165,824
    float*  l   = (float*)(ws + 104202240);     // 32,768
    ushort* P   = (ushort*)(ws + 0);            // 33,554,432 (alias X)
    float*  O1  = (float*)(ws + 41287680);      // 25,165,824 (alias qb+kb)

    (void)in_sizes; (void)n_in; (void)out_size; (void)ws_size;

    hipMemsetAsync(l, 0, NROWS * sizeof(float), stream);

    // 1) gather sparsified rows -> bf16 (z = Q/K/V)
    pack3<<<dim3(6144, 1, 3), 256, 0, stream>>>(Q, K_, V, Xq);
    // 2) weights -> bf16 (z = Wq/Wk/Wv)
    conv3<<<dim3(576, 1, 3), 256, 0, stream>>>(Wq, Wk, Wv, Wqb);

    // 3) projections: z in {q,k,v}; v stores transposed (vT)
    gemm_bt<0><<<dim3(DIM / GTILE, NROWS / GTILE, 3), 256, 0, stream>>>(
        Xq, Wqb, qb, vT, nullptr, nullptr, nullptr,
        NROWS, DIM, DIM, DIM, DIM,
        (long)NROWS * DIM, (long)DIM * DIM, (long)NROWS * DIM, DIM, 0.f);

    // 4) LayerNorm q and k in place (qb,kb contiguous: 16384 rows)
    ln_inplace<<<4096, 256, 0, stream>>>(qb, g, b);

    // 5) P = exp(scale * q k^T), row-sums into l
    gemm_bt<2><<<dim3(LSP / GTILE, LSP / GTILE, BATCH), 256, 0, stream>>>(
        qb, kb, P, nullptr, nullptr, nullptr, l,
        LSP, LSP, DIM, DIM, DIM,
        (long)LSP * DIM, (long)LSP * DIM, (long)LSP * LSP, LSP, ATT_SCALE);

    // 6) O = P @ v, split-K x2 (z = batch*2 + half), B operand = vT
    gemm_bt<3><<<dim3(DIM / GTILE, LSP / GTILE, BATCH * 2), 256, 0, stream>>>(
        P, vT, nullptr, nullptr, O0, O1, nullptr,
        LSP, DIM, LSP / 2, LSP, LSP,
        (long)LSP * LSP, (long)DIM * LSP, (long)LSP * DIM, DIM, 0.f);

    // 7) out = softmax_d((O0+O1) / l)
    final_softmax<<<2048, 256, 0, stream>>>(O0, O1, l, out);
}

// Round 4
// 457.131 us; speedup vs baseline: 1.0064x; 1.0064x over previous
//
#include <hip/hip_runtime.h>
#include <math.h>

// Problem constants (B=4, L=8192, SEG=2048, RATE=4, D=768)
#define SEGLEN 2048
#define SRATE 4
#define DIM 768
#define BATCH 4
#define LFULL 8192
#define LSP 2048                 // sparsified length per batch (4 segs * 512)
#define NROWS (BATCH * LSP)      // 8192 total sparsified rows
#define LN_EPS 1e-5f
#define ATT_SCALE 0.03608439182435161f   // 1/sqrt(768)

typedef __attribute__((ext_vector_type(8))) short s16x8;
typedef __attribute__((ext_vector_type(4))) float f32x4;

__device__ __forceinline__ ushort f2bf(float f) {
    unsigned u = __float_as_uint(f);
    u += 0x7fffu + ((u >> 16) & 1u);      // RNE
    return (ushort)(u >> 16);
}
__device__ __forceinline__ float bf2f(ushort h) {
    return __uint_as_float(((unsigned)h) << 16);
}

// async global->LDS, 16B per lane. LDS dest is wave-uniform base + lane*16.
__device__ __forceinline__ void ld_lds16(const ushort* g, ushort* l) {
    __builtin_amdgcn_global_load_lds(
        (const __attribute__((address_space(1))) void*)g,
        (__attribute__((address_space(3))) void*)l, 16, 0, 0);
}

// ---------------------------------------------------------------------------
// Gather sparsified rows (every RATE-th within each segment) + fp32->bf16.
// z selects Q/K/V. dst r = b*2048 + seg*512 + j <- src[b*8192 + seg*2048 + j*4]
// ---------------------------------------------------------------------------
__global__ void pack3(const float* __restrict__ Q, const float* __restrict__ Ks,
                      const float* __restrict__ V, ushort* __restrict__ X) {
    const float* src = blockIdx.z == 0 ? Q : blockIdx.z == 1 ? Ks : V;
    ushort* dst = X + (long)blockIdx.z * (NROWS * DIM);
    int idx = blockIdx.x * 256 + threadIdx.x;        // one per 4 elements
    int r  = idx / (DIM / 4);
    int dg = idx - r * (DIM / 4);
    int bb = r >> 11;            // /2048
    int s  = r & 2047;
    int seg = s >> 9;            // /512
    int j   = s & 511;
    long srow = (long)bb * LFULL + seg * SEGLEN + j * SRATE;
    float4 f = *(const float4*)(src + srow * DIM + dg * 4);
    ushort4 o;
    o.x = f2bf(f.x); o.y = f2bf(f.y); o.z = f2bf(f.z); o.w = f2bf(f.w);
    *(ushort4*)(dst + (long)r * DIM + dg * 4) = o;
}

// weights fp32 -> bf16, z selects Wq/Wk/Wv; dst contiguous
__global__ void conv3(const float* __restrict__ Wq, const float* __restrict__ Wk,
                      const float* __restrict__ Wv, ushort* __restrict__ W) {
    const float* src = blockIdx.z == 0 ? Wq : blockIdx.z == 1 ? Wk : Wv;
    ushort* dst = W + (long)blockIdx.z * (DIM * DIM);
    int idx = blockIdx.x * 256 + threadIdx.x;
    float4 f = *(const float4*)(src + (long)idx * 4);
    ushort4 o;
    o.x = f2bf(f.x); o.y = f2bf(f.y); o.z = f2bf(f.z); o.w = f2bf(f.w);
    *(ushort4*)(dst + (long)idx * 4) = o;
}

// ---------------------------------------------------------------------------
// BT-GEMM: C[i][j] = sum_k A[i][k] * B[j][k]  (both operands K-contiguous bf16)
// 128x128 tile, BK=32, 256 thr = 4 waves (2x2), each wave 64x64 (4x4 MFMA).
// Pipelined K-loop: double-buffered LDS (2 x 8KB per operand), prefetch tile
// i+1 via global_load_lds right after barrier i, then compute tile i -> the
// vmcnt(0) drain at barrier i+1 covers a load that had the compute phase to
// land (exposed latency ~ max(0, load - compute) instead of full latency).
// LDS layout: slab = 8 rows x 64B, within slab [kchunk(4)][row&7] 16B chunks
// -> any 8 consecutive lanes of ds_read_b128 cover 128B contiguous = 32 banks
// once = zero conflicts (verified: SQ_LDS_BANK_CONFLICT==0 with this scheme).
// XCD-band swizzle: xcd gets a contiguous tile band (FETCH 117->33 MB).
// MODE 0: z<2 -> bf16 row-major to Cb+z*sC; z==2 -> transposed vT to Cb2 [proj]
// MODE 2: e=__expf(acc*scale); bf16 P row-major (row-sums done separately)[QK]
// MODE 3: split-K: z=(batch,half); fp32 row-major to (half? Cf2 : Cf)     [PV]
// ---------------------------------------------------------------------------
#define GTILE 128
#define GBK 32

template<int MODE>
__global__ __launch_bounds__(256) void gemm_bt(
    const ushort* __restrict__ Ag, const ushort* __restrict__ Bg,
    ushort* __restrict__ Cb, ushort* __restrict__ Cb2,
    float* __restrict__ Cf, float* __restrict__ Cf2,
    int M, int N, int K, int lda, int ldb, long sA, long sB, long sC,
    int ldc, float scale)
{
    __shared__ ushort As[2 * GTILE * GBK];   // 2 x 8 KB
    __shared__ ushort Bs[2 * GTILE * GBK];

    // XCD-band swizzle (total blocks % 8 == 0 for all launches here)
    const int CT = gridDim.x, RT = gridDim.y;
    const int nt = CT * RT;
    const int total = nt * gridDim.z;
    int g = (blockIdx.z * RT + blockIdx.y) * CT + blockIdx.x;
    g = (g & 7) * (total >> 3) + (g >> 3);
    const int z = g / nt;
    const int rem = g - z * nt;
    const int by = rem / CT, bx = rem - by * CT;

    const int bz = (MODE == 3) ? (z >> 1) : z;
    const int hz = (MODE == 3) ? (z & 1) : 0;
    const ushort* A = Ag + (long)bz * sA + (long)hz * K;
    const ushort* B = Bg + (long)bz * sB + (long)hz * K;

    const int tid = threadIdx.x;
    const int rowBase = by * GTILE;
    const int colBase = bx * GTILE;
    const int wid = tid >> 6, lane = tid & 63;
    const int wm = wid >> 1, wn = wid & 1;
    const int quad = lane >> 4, lr = lane & 15;

    f32x4 acc[4][4] = {};

    // Staging (per wave, 2 instrs per operand, 1KB each covering 2 slabs):
    // instr j: lane l fetches row wid*32 + j*16 + (l>>5)*8 + (l&7),
    //          kchunk (l>>3)&3 -> LDS dest = base + wid*1024 + j*512 + l*8.
    const int srow = wid * 32 + ((lane >> 5) << 3) + (lane & 7);
    const int skc  = ((lane >> 3) & 3) * 8;
    const ushort* gA0 = A + (long)(rowBase + srow) * lda + skc;
    const ushort* gA1 = A + (long)(rowBase + srow + 16) * lda + skc;
    const ushort* gB0 = B + (long)(colBase + srow) * ldb + skc;
    const ushort* gB1 = B + (long)(colBase + srow + 16) * ldb + skc;
    ushort* lAw = As + wid * 1024;   // wave-uniform
    ushort* lBw = Bs + wid * 1024;

    // frag read offsets (ushorts): slab*256 + kchunk*64 + (row&7)*8
    // A row = wm*64 + t*16 + lr -> slab = wm*8 + t*2 + (lr>>3)
    const int fra = (wm * 8 + (lr >> 3)) * 256 + quad * 64 + (lr & 7) * 8;
    const int frb = (wn * 8 + (lr >> 3)) * 256 + quad * 64 + (lr & 7) * 8;

    const int NI = K / GBK;
    // prologue: stage tile 0 into buffer 0
    ld_lds16(gA0, lAw);
    ld_lds16(gA1, lAw + 512);
    ld_lds16(gB0, lBw);
    ld_lds16(gB1, lBw + 512);

    for (int i = 0; i < NI; i++) {
        __syncthreads();   // drains vmcnt: buf[i&1] staged; prev ds_reads done
        if (i + 1 < NI) {
            const int nb = (i + 1) & 1;
            const int k0 = (i + 1) * GBK;
            ld_lds16(gA0 + k0, lAw + nb * 4096);
            ld_lds16(gA1 + k0, lAw + nb * 4096 + 512);
            ld_lds16(gB0 + k0, lBw + nb * 4096);
            ld_lds16(gB1 + k0, lBw + nb * 4096 + 512);
        }
        const ushort* Ab = As + (i & 1) * 4096;
        const ushort* Bb = Bs + (i & 1) * 4096;
        s16x8 af[4], bfm[4];
#pragma unroll
        for (int t = 0; t < 4; t++)
            af[t] = *(const s16x8*)&Ab[fra + t * 512];
#pragma unroll
        for (int t = 0; t < 4; t++)
            bfm[t] = *(const s16x8*)&Bb[frb + t * 512];
#pragma unroll
        for (int i2 = 0; i2 < 4; i2++)
#pragma unroll
            for (int j = 0; j < 4; j++)
                acc[i2][j] = __builtin_amdgcn_mfma_f32_16x16x32_bf16(af[i2], bfm[j], acc[i2][j], 0, 0, 0);
    }

    // Epilogue. D mapping: col = lane&15 (B-operand row), row = quad*4+reg.
    if (MODE == 0) {
        if (z < 2) {
            ushort* Cz = Cb + (long)z * sC;
#pragma unroll
            for (int i = 0; i < 4; i++) {
                int r0 = rowBase + wm * 64 + i * 16 + quad * 4;
#pragma unroll
                for (int j = 0; j < 4; j++) {
                    int c = colBase + wn * 64 + j * 16 + lr;
#pragma unroll
                    for (int reg = 0; reg < 4; reg++)
                        Cz[(long)(r0 + reg) * ldc + c] = f2bf(acc[i][j][reg]);
                }
            }
        } else {
            // v-projection: store transposed vT[b][col][row]
#pragma unroll
            for (int i = 0; i < 4; i++) {
                int r0 = rowBase + wm * 64 + i * 16 + quad * 4;
                int bidx = r0 >> 11;
                int jj = r0 & 2047;
                ushort* Cz = Cb2 + (long)bidx * DIM * LSP;
#pragma unroll
                for (int j = 0; j < 4; j++) {
                    int c = colBase + wn * 64 + j * 16 + lr;
                    ushort4 o;
                    o.x = f2bf(acc[i][j][0]); o.y = f2bf(acc[i][j][1]);
                    o.z = f2bf(acc[i][j][2]); o.w = f2bf(acc[i][j][3]);
                    *(ushort4*)(Cz + (long)c * LSP + jj) = o;
                }
            }
        }
    } else if (MODE == 2) {
        ushort* Cz = Cb + (long)z * sC;
#pragma unroll
        for (int i = 0; i < 4; i++) {
            int r0 = rowBase + wm * 64 + i * 16 + quad * 4;
#pragma unroll
            for (int j = 0; j < 4; j++) {
                int c = colBase + wn * 64 + j * 16 + lr;
#pragma unroll
                for (int reg = 0; reg < 4; reg++)
                    Cz[(long)(r0 + reg) * ldc + c] =
                        f2bf(__expf(acc[i][j][reg] * scale)); // |logit|<=sqrt(768)
            }
        }
    } else { // MODE 3 split-K
        float* Cz = (hz ? Cf2 : Cf) + (long)bz * sC;
#pragma unroll
        for (int i = 0; i < 4; i++) {
            int r0 = rowBase + wm * 64 + i * 16 + quad * 4;
#pragma unroll
            for (int j = 0; j < 4; j++) {
                int c = colBase + wn * 64 + j * 16 + lr;
#pragma unroll
                for (int reg = 0; reg < 4; reg++)
                    Cz[(long)(r0 + reg) * ldc + c] = acc[i][j][reg];
            }
        }
    }
}

// ---------------------------------------------------------------------------
// l[row] = sum over 2048 bf16 of P[row][:]. One wave per row, 4 rows/block.
// ---------------------------------------------------------------------------
__global__ __launch_bounds__(256) void row_sums(
    const ushort* __restrict__ P, float* __restrict__ l)
{
    int wid = threadIdx.x >> 6, lane = threadIdx.x & 63;
    int row = blockIdx.x * 4 + wid;
    const ushort* pp = P + (long)row * LSP;
    float s = 0.f;
#pragma unroll
    for (int c = 0; c < 8; c++) {
        ushort4 u = *(const ushort4*)(pp + (c * 64 + lane) * 4);
        s += bf2f(u.x) + bf2f(u.y) + bf2f(u.z) + bf2f(u.w);
    }
    for (int m = 1; m < 64; m <<= 1) s += __shfl_xor(s, m, 64);
    if (lane == 0) l[row] = s;
}

// ---------------------------------------------------------------------------
// In-place LayerNorm over DIM=768 bf16 values. One wave per row (12 elem/lane).
// ---------------------------------------------------------------------------
__global__ __launch_bounds__(256) void ln_inplace(
    ushort* __restrict__ X, const float* __restrict__ gamma,
    const float* __restrict__ beta)
{
    int wid = threadIdx.x >> 6, lane = threadIdx.x & 63;
    int row = blockIdx.x * 4 + wid;
    ushort* xp = X + (long)row * DIM;
    float v[12];
    float s = 0.f;
#pragma unroll
    for (int c = 0; c < 12; c++) { v[c] = bf2f(xp[c * 64 + lane]); s += v[c]; }
    for (int m = 1; m < 64; m <<= 1) s += __shfl_xor(s, m, 64);
    float mean = s * (1.0f / 768.0f);
    float q = 0.f;
#pragma unroll
    for (int c = 0; c < 12; c++) { float d = v[c] - mean; q += d * d; }
    for (int m = 1; m < 64; m <<= 1) q += __shfl_xor(q, m, 64);
    float rstd = rsqrtf(q * (1.0f / 768.0f) + LN_EPS);
#pragma unroll
    for (int c = 0; c < 12; c++) {
        int idx = c * 64 + lane;
        float y = (v[c] - mean) * rstd * gamma[idx] + beta[idx];
        xp[idx] = f2bf(y);
    }
}

// ---------------------------------------------------------------------------
// out[row] = softmax_over_d( (O0[row]+O1[row]) / l[row] ). One wave per row.
// ---------------------------------------------------------------------------
__global__ __launch_bounds__(256) void final_softmax(
    const float* __restrict__ O0, const float* __restrict__ O1,
    const float* __restrict__ l, float* __restrict__ out)
{
    int wid = threadIdx.x >> 6, lane = threadIdx.x & 63;
    int row = blockIdx.x * 4 + wid;
    long base = (long)row * DIM;
    float inv = 1.0f / l[row];
    float v[12]; float mx = -1e30f;
#pragma unroll
    for (int c = 0; c < 12; c++) {
        v[c] = (O0[base + c * 64 + lane] + O1[base + c * 64 + lane]) * inv;
        mx = fmaxf(mx, v[c]);
    }
    for (int m = 1; m < 64; m <<= 1) mx = fmaxf(mx, __shfl_xor(mx, m, 64));
    float s = 0.f;
#pragma unroll
    for (int c = 0; c < 12; c++) { v[c] = __expf(v[c] - mx); s += v[c]; }
    for (int m = 1; m < 64; m <<= 1) s += __shfl_xor(s, m, 64);
    float invs = 1.0f / s;
#pragma unroll
    for (int c = 0; c < 12; c++) out[base + c * 64 + lane] = v[c] * invs;
}

// ---------------------------------------------------------------------------
extern "C" void kernel_launch(void* const* d_in, const int* in_sizes, int n_in,
                              void* d_out, int out_size, void* d_ws, size_t ws_size,
                              hipStream_t stream)
{
    const float* Q  = (const float*)d_in[0];
    const float* K_ = (const float*)d_in[1];
    const float* V  = (const float*)d_in[2];
    const float* Wq = (const float*)d_in[3];
    const float* Wk = (const float*)d_in[4];
    const float* Wv = (const float*)d_in[5];
    const float* g  = (const float*)d_in[6];
    const float* b  = (const float*)d_in[7];
    float* out = (float*)d_out;

    char* ws = (char*)d_ws;
    // Workspace layout (bytes). Total ~104.3 MB.
    // P aliases X (lifetime-disjoint); O1 aliases qb+kb (dead after QK).
    ushort* Xq  = (ushort*)(ws + 0);            // 12,582,912 each (Xq,Xk,Xv contig)
    ushort* Wqb = (ushort*)(ws + 37748736);     // 1,179,648 each (contig)
    ushort* qb  = (ushort*)(ws + 41287680);     // 12,582,912 each (qb,kb contig)
    ushort* kb  = (ushort*)(ws + 53870592);
    ushort* vT  = (ushort*)(ws + 66453504);     // 12,582,912
    float*  O0  = (float*)(ws + 79036416);      // 25,165,824
    float*  l   = (float*)(ws + 104202240);     // 32,768
    ushort* P   = (ushort*)(ws + 0);            // 33,554,432 (alias X)
    float*  O1  = (float*)(ws + 41287680);      // 25,165,824 (alias qb+kb)

    (void)in_sizes; (void)n_in; (void)out_size; (void)ws_size;

    // 1) gather sparsified rows -> bf16 (z = Q/K/V)
    pack3<<<dim3(6144, 1, 3), 256, 0, stream>>>(Q, K_, V, Xq);
    // 2) weights -> bf16 (z = Wq/Wk/Wv)
    conv3<<<dim3(576, 1, 3), 256, 0, stream>>>(Wq, Wk, Wv, Wqb);

    // 3) projections: z in {q,k,v}; v stores transposed (vT)
    gemm_bt<0><<<dim3(DIM / GTILE, NROWS / GTILE, 3), 256, 0, stream>>>(
        Xq, Wqb, qb, vT, nullptr, nullptr,
        NROWS, DIM, DIM, DIM, DIM,
        (long)NROWS * DIM, (long)DIM * DIM, (long)NROWS * DIM, DIM, 0.f);

    // 4) LayerNorm q and k in place (qb,kb contiguous: 16384 rows)
    ln_inplace<<<4096, 256, 0, stream>>>(qb, g, b);

    // 5) P = exp(scale * q k^T)
    gemm_bt<2><<<dim3(LSP / GTILE, LSP / GTILE, BATCH), 256, 0, stream>>>(
        qb, kb, P, nullptr, nullptr, nullptr,
        LSP, LSP, DIM, DIM, DIM,
        (long)LSP * DIM, (long)LSP * DIM, (long)LSP * LSP, LSP, ATT_SCALE);

    // 5b) l = row-sums of P
    row_sums<<<2048, 256, 0, stream>>>(P, l);

    // 6) O = P @ v, split-K x2 (z = batch*2 + half), B operand = vT
    gemm_bt<3><<<dim3(DIM / GTILE, LSP / GTILE, BATCH * 2), 256, 0, stream>>>(
        P, vT, nullptr, nullptr, O0, O1,
        LSP, DIM, LSP / 2, LSP, LSP,
        (long)LSP * LSP, (long)DIM * LSP, (long)LSP * DIM, DIM, 0.f);

    // 7) out = softmax_d((O0+O1) / l)
    final_softmax<<<2048, 256, 0, stream>>>(O0, O1, l, out);
}